// Round 10
// baseline (286.734 us; speedup 1.0000x reference)
//
#include <hip/hip_runtime.h>
#include <math.h>

// Problem constants
#define B_    32
#define C3_   1024
#define C4_   2048
#define C_    3072
#define P_    784      // 28*28
#define Q_    196      // 14*14
#define L_    9
#define NG_   25088    // B_*P_
#define A_    312
#define NC_   200

// d_out layout (floats): attr(32x312), class(32x200), maps(32x9x784), af(32x3072x9)
#define ATTR_OFF  0
#define CLASS_OFF 9984
#define MAPS_OFF  16384
#define AF_OFF    242176

// workspace layout (floats)
#define ASQ_OFF   0
#define MF_OFF    16
#define LOGITS_OFF 98320                          // 9 x NG_ = 225792
#define Y_OFF     (LOGITS_OFF + 9 * NG_)          // 324112 ; 32 x 9 x 196
#define MP_OFF    (Y_OFF + 32 * 9 * Q_)           // 380560 ; 32 x 9 x 196
// NOTE: zK zeroes [LOGITS_OFF, Y_OFF+32*9*Q_) as ONE contiguous float4 range
// (282240 floats = 70560 float4) -- logits and Y must stay adjacent.

typedef __attribute__((ext_vector_type(8))) short bf16x8;
typedef __attribute__((ext_vector_type(4))) float f32x4;

__device__ __forceinline__ short f2bf(float f) {
    union { float f; unsigned u; } v; v.f = f;
    unsigned r = v.u + 0x7FFFu + ((v.u >> 16) & 1u);   // RNE
    return (short)(r >> 16);
}

// async global->LDS, 16B per lane, LDS dest = uniform base + lane*16
#define GLDS16(gp, lp) __builtin_amdgcn_global_load_lds(                    \
        (const __attribute__((address_space(1))) unsigned int*)(gp),        \
        (__attribute__((address_space(3))) unsigned int*)(lp), 16, 0, 0)

// ============ zK (v9): blocks 0..8 compute asq[l] in parallel (float4);
// blocks 9..284 zero logits+Y as float4 (70560 vecs).
__global__ __launch_bounds__(256) void zK(const float* __restrict__ conv_w,
                                          float* __restrict__ zbase,
                                          float* __restrict__ asq) {
    int bx = blockIdx.x, t = threadIdx.x;
    if (bx < 9) {
        __shared__ float red[256];
        const float4* w = (const float4*)(conv_w + (size_t)bx * C_);
        float s = 0.f;
#pragma unroll
        for (int i = 0; i < 3; ++i) {        // 768 float4 = 3 x 256
            float4 v = w[t + i * 256];
            s += v.x + v.y + v.z + v.w;
        }
        red[t] = s; __syncthreads();
        for (int o = 128; o > 0; o >>= 1) {
            if (t < o) red[t] += red[t + o];
            __syncthreads();
        }
        if (t == 0) asq[bx] = red[0];
        return;
    }
    int i = (bx - 9) * 256 + t;
    if (i < 70560)
        ((float4*)zbase)[i] = make_float4(0.f, 0.f, 0.f, 0.f);
}

// ============================================================= K_A (round-4)
// Best measured engine (65us): chunked GLDS pipeline, 2x16KB LDS dbuf
// (5 blk/CU), 64ch = 4 chunks of 16, counted vmcnt(4), device-scope atomic
// epilogue into logits (x2) / Y.
//   blocks [0,1568): l3.  slab = bid/98, g-tile = bid%98.
//   blocks [1568,2592): l4. b = idx>>5, grp = idx&31.
__global__ __launch_bounds__(256, 5) void kA(
        const float* __restrict__ l3, const float* __restrict__ l4,
        const float* __restrict__ conv_w,
        float* __restrict__ logits, float* __restrict__ Y) {
    __shared__ float X[2][16 * 256];   // 32768 B -> 5 blocks/CU
    int bid = blockIdx.x;
    int t = threadIdx.x;
    int wave = t >> 6, lane = t & 63;

    bool isl3 = (bid < 1568);
    int slab = 0, g0 = 0, b = 0, grp = 0, cbase_w;
    const float* gbase;     // per-lane base address for channel-row 0
    size_t rowpitch;
    if (isl3) {
        slab = bid / 98;                 // block-uniform
        g0 = (bid % 98) * 256;
        int gidx = g0 + lane * 4;        // 4 floats (16B) per lane
        int bb = gidx / 784, px = gidx % 784;   // 4 | 784 -> no group split
        gbase = l3 + ((size_t)bb * C3_ + slab * 64) * P_ + px;
        rowpitch = P_;
        cbase_w = C4_ + slab * 64;
    } else {
        int idx = bid - 1568;
        b = idx >> 5; grp = idx & 31;    // block-uniform
        int q = lane * 4;
        if (q > 192) q = 192;            // lanes 49..63: dup same 16B (1 line)
        gbase = l4 + ((size_t)b * C4_ + grp * 64) * Q_ + q;
        rowpitch = Q_;
        cbase_w = grp * 64;
    }

    // prologue: chunk 0 -> buf 0 (wave w stages in-chunk rows w*4..w*4+3)
#pragma unroll
    for (int r = 0; r < 4; ++r) {
        int row = wave * 4 + r;
        GLDS16(gbase + (size_t)row * rowpitch, &X[0][row * 256]);
    }

    float acc[9];
#pragma unroll
    for (int l = 0; l < 9; ++l) acc[l] = 0.f;

#pragma unroll
    for (int j = 0; j < 4; ++j) {
        const int cur = j & 1;
        if (j < 3) {
#pragma unroll
            for (int r = 0; r < 4; ++r) {
                int row = wave * 4 + r;           // in-chunk row
                int ch = (j + 1) * 16 + row;      // global channel row
                GLDS16(gbase + (size_t)ch * rowpitch, &X[cur ^ 1][row * 256]);
            }
            // counted wait: own chunk-j loads (oldest 4) done; chunk j+1's
            // 4 loads stay in flight across the barrier.
            asm volatile("s_waitcnt vmcnt(4)" ::: "memory");
        } else {
            asm volatile("s_waitcnt vmcnt(0)" ::: "memory");
        }
        __builtin_amdgcn_s_barrier();      // all waves' chunk-j rows in LDS

        if (isl3 || t < 196) {
#pragma unroll
            for (int c = 0; c < 16; ++c) {
                float x = X[cur][c * 256 + t];
#pragma unroll
                for (int l = 0; l < 9; ++l)
                    acc[l] = fmaf(conv_w[(size_t)l * C_ + cbase_w + j * 16 + c],
                                  x, acc[l]);
            }
        }
        __builtin_amdgcn_s_barrier();      // reads done before buf reuse
    }

    if (isl3) {
#pragma unroll
        for (int l = 0; l < 9; ++l)
            atomicAdd(&logits[(size_t)l * NG_ + g0 + t], 2.f * acc[l]);
    } else if (t < 196) {
#pragma unroll
        for (int l = 0; l < 9; ++l)
            atomicAdd(&Y[((size_t)b * 9 + l) * Q_ + t], acc[l]);
    }
}

// ====== K_CD (v10): fused maps-softmax + adjoint downsample, 1 block per b.
// Phase 1: stage Y[b] (7KB) + asq in LDS; per pixel p read 9 logits, add
// 2*upsample(Y) - asq, softmax, write maps to global AND LDS.
// Phase 2: adjoint bilinear downsample from LDS maps -> Mp.
// Replaces kC (98 blk) + kD (221 blk): one launch fewer, kills the maps
// re-read and the 36 scattered Y loads per pixel.
__device__ __forceinline__ int adj_taps(int q, int* ys, float* wy) {
    if (q == 0)  { ys[0] = 0;  wy[0] = 1.00f; ys[1] = 1;  wy[1] = 0.75f;
                   ys[2] = 2;  wy[2] = 0.25f; return 3; }
    if (q == 13) { ys[0] = 25; wy[0] = 0.25f; ys[1] = 26; wy[1] = 0.75f;
                   ys[2] = 27; wy[2] = 1.00f; return 3; }
    ys[0] = 2 * q - 1; wy[0] = 0.25f;
    ys[1] = 2 * q;     wy[1] = 0.75f;
    ys[2] = 2 * q + 1; wy[2] = 0.75f;
    ys[3] = 2 * q + 2; wy[3] = 0.25f;
    return 4;
}

__global__ __launch_bounds__(256) void kCD(const float* __restrict__ logits,
                                           const float* __restrict__ Y,
                                           const float* __restrict__ asq,
                                           float* __restrict__ out_maps,
                                           float* __restrict__ Mp) {
    __shared__ float sm[9 * 784];     // 28224 B
    __shared__ float sy[9 * 196];     //  7056 B
    __shared__ float sa[9];
    int b = blockIdx.x, t = threadIdx.x;

    for (int i = t; i < 9 * Q_; i += 256) sy[i] = Y[(size_t)b * (9 * Q_) + i];
    if (t < 9) sa[t] = asq[t];
    __syncthreads();

    // ---- phase 1: softmax over l -> maps (global + LDS) ----
    for (int p = t; p < P_; p += 256) {
        int yy = p / 28, xx = p % 28;
        float sy_ = 0.5f * yy - 0.25f, sx_ = 0.5f * xx - 0.25f;
        float fyf = floorf(sy_), fxf = floorf(sx_);
        float fy = sy_ - fyf, fx = sx_ - fxf;
        int ya = max(0, (int)fyf), yb = min(13, (int)fyf + 1);
        int xa = max(0, (int)fxf), xb = min(13, (int)fxf + 1);
        float w00 = (1.f - fy) * (1.f - fx), w01 = (1.f - fy) * fx;
        float w10 = fy * (1.f - fx),         w11 = fy * fx;
        float v[9];
#pragma unroll
        for (int l = 0; l < 9; ++l) {
            const float* Yl = sy + l * Q_;
            float ab4 = w00 * Yl[ya * 14 + xa] + w01 * Yl[ya * 14 + xb]
                      + w10 * Yl[yb * 14 + xa] + w11 * Yl[yb * 14 + xb];
            v[l] = logits[(size_t)l * NG_ + b * P_ + p] + 2.f * ab4 - sa[l];
        }
        float m = v[0];
#pragma unroll
        for (int l = 1; l < 9; ++l) m = fmaxf(m, v[l]);
        float sum = 0.f;
#pragma unroll
        for (int l = 0; l < 9; ++l) { v[l] = expf(v[l] - m); sum += v[l]; }
        float inv = 1.f / sum;
#pragma unroll
        for (int l = 0; l < 9; ++l) {
            float mv = v[l] * inv;
            sm[l * P_ + p] = mv;
            out_maps[(size_t)b * (L_ * P_) + l * P_ + p] = mv;
        }
    }
    __syncthreads();

    // ---- phase 2: adjoint bilinear downsample from LDS ----
    for (int r = t; r < 9 * Q_; r += 256) {
        int l = r / Q_, q = r % Q_;
        int qy = q / 14, qx = q % 14;
        int ys[4], xs[4]; float wy[4], wx[4];
        int ny = adj_taps(qy, ys, wy);
        int nx = adj_taps(qx, xs, wx);
        const float* mrow = sm + l * P_;
        float s = 0.f;
        for (int i = 0; i < ny; ++i) {
            float rs = 0.f;
            for (int j = 0; j < nx; ++j)
                rs = fmaf(wx[j], mrow[ys[i] * 28 + xs[j]], rs);
            s = fmaf(wy[i], rs, s);
        }
        Mp[(size_t)b * (9 * Q_) + r] = s;
    }
}

// ===================== K_E (v10): direct-global MFMA, heavy blocks FIRST
// l3 blocks (4 K-chunks, 4x work) now bid<512 so the scheduler issues them
// early (they were last -> pure load-imbalance tail).
// blocks [0,512): l3, b=bid>>4, grp 0..15, K=784 (4 chunks, acc carried).
// blocks [512,1536): l4, b=idx>>5, grp 0..31, K=196 (1 chunk) vs Mp.
// Epilogue: af FINAL (/784) + mf via 16-lane shfl tree.
__global__ __launch_bounds__(256, 3) void kE(
        const float* __restrict__ l3, const float* __restrict__ l4,
        const float* __restrict__ maps, const float* __restrict__ Mp,
        const float* __restrict__ mod,
        float* __restrict__ out_af, float* __restrict__ mf) {
    int bid = blockIdx.x;
    int t = threadIdx.x;
    int wave = t >> 6, lane = t & 63;
    int row16 = lane & 15, quad = lane >> 4;

    bool isl3 = (bid < 512);
    int b, c0, nchunk, cglob0, pitch;
    const float* xsrc; const float* bsrc;
    if (isl3) {
        b = bid >> 4; c0 = (bid & 15) * 64; nchunk = 4;
        xsrc = l3 + ((size_t)b * C3_ + c0) * P_;
        bsrc = maps + (size_t)b * (L_ * P_);
        pitch = P_;
        cglob0 = C4_ + c0;
    } else {
        int idx = bid - 512;
        b = idx >> 5; c0 = (idx & 31) * 64; nchunk = 1;
        xsrc = l4 + ((size_t)b * C4_ + c0) * Q_;
        bsrc = Mp + (size_t)b * (9 * Q_);
        pitch = Q_;
        cglob0 = c0;
    }
    const float* arow = xsrc + (size_t)(wave * 16 + row16) * pitch;
    const float* brow = bsrc + (size_t)row16 * pitch;   // valid if row16 < 9

    f32x4 acc = {0.f, 0.f, 0.f, 0.f};
    for (int h = 0; h < nchunk; ++h) {
        int koff = h * 196;
        float4 a[13];
#pragma unroll
        for (int s = 0; s < 6; ++s) {
            int k0 = koff + s * 32 + quad * 8;
            a[2 * s]     = *(const float4*)(arow + k0);
            a[2 * s + 1] = *(const float4*)(arow + k0 + 4);
        }
        a[12] = make_float4(0.f, 0.f, 0.f, 0.f);
        if (quad == 0) a[12] = *(const float4*)(arow + koff + 192);

        bf16x8 bfr[7];
#pragma unroll
        for (int s = 0; s < 7; ++s) {
            int k0 = s * 32 + quad * 8;
            bf16x8 bv = {0, 0, 0, 0, 0, 0, 0, 0};
            if (row16 < 9) {
                const float* bp = brow + koff + k0;
                if (s < 6) {
                    float4 b0 = *(const float4*)(bp);
                    float4 b1 = *(const float4*)(bp + 4);
                    bv[0] = f2bf(b0.x); bv[1] = f2bf(b0.y);
                    bv[2] = f2bf(b0.z); bv[3] = f2bf(b0.w);
                    bv[4] = f2bf(b1.x); bv[5] = f2bf(b1.y);
                    bv[6] = f2bf(b1.z); bv[7] = f2bf(b1.w);
                } else if (quad == 0) {        // k0=192: cols 192..195 only
                    float4 b0 = *(const float4*)(bp);
                    bv[0] = f2bf(b0.x); bv[1] = f2bf(b0.y);
                    bv[2] = f2bf(b0.z); bv[3] = f2bf(b0.w);
                }
            }
            bfr[s] = bv;
        }

#pragma unroll
        for (int s = 0; s < 7; ++s) {
            bf16x8 av = {0, 0, 0, 0, 0, 0, 0, 0};
            if (s < 6) {
                float4 a0 = a[2 * s], a1 = a[2 * s + 1];
                av[0] = f2bf(a0.x); av[1] = f2bf(a0.y);
                av[2] = f2bf(a0.z); av[3] = f2bf(a0.w);
                av[4] = f2bf(a1.x); av[5] = f2bf(a1.y);
                av[6] = f2bf(a1.z); av[7] = f2bf(a1.w);
            } else if (quad == 0) {
                float4 a0 = a[12];
                av[0] = f2bf(a0.x); av[1] = f2bf(a0.y);
                av[2] = f2bf(a0.z); av[3] = f2bf(a0.w);
            }
            acc = __builtin_amdgcn_mfma_f32_16x16x32_bf16(av, bfr[s], acc,
                                                          0, 0, 0);
        }
    }

    // ---- epilogue: af (final) + mf (verified r4/r7 scheme) ----
    int l = row16;
    int cg = cglob0 + wave * 16 + quad * 4;
    float afv[4];
#pragma unroll
    for (int r = 0; r < 4; ++r) afv[r] = acc[r] * (1.f / 784.f);
    if (l < 9) {
        size_t base = ((size_t)b * C_ + cg) * 9 + l;
#pragma unroll
        for (int r = 0; r < 4; ++r) out_af[base + (size_t)r * 9] = afv[r];
    }
    float term[4];
#pragma unroll
    for (int r = 0; r < 4; ++r)
        term[r] = (l < 8) ? afv[r] * mod[(size_t)(cg + r) * 9 + l] : 0.f;
#pragma unroll
    for (int s = 1; s < 16; s <<= 1)
#pragma unroll
        for (int r = 0; r < 4; ++r) term[r] += __shfl_xor(term[r], s);
    if (row16 == 0) {
#pragma unroll
        for (int r = 0; r < 4; ++r)
            mf[(size_t)b * C_ + cg + r] = term[r] * 0.125f;
    }
}

// ============== K_F (v9): attr = mf @ attr_w.T, attr_w staged ONCE per block
__global__ __launch_bounds__(256) void kF(
        const float* __restrict__ mf, const float* __restrict__ attr_w,
        const float* __restrict__ attr_b, float* __restrict__ out_attr) {
    __shared__ float sw[C_];               // 12288 B
    int a = blockIdx.x, t = threadIdx.x;
    const float4* wr = (const float4*)(attr_w + (size_t)a * C_);
#pragma unroll
    for (int i = 0; i < 3; ++i)            // 768 float4 = 3 x 256
        ((float4*)sw)[t + i * 256] = wr[t + i * 256];
    __syncthreads();

    int b = t >> 3, j = t & 7;             // 8 lanes per batch
    const float* mrow = mf + (size_t)b * C_;
    float acc = 0.f;
#pragma unroll 8
    for (int m = 0; m < 96; ++m) {         // k = j*4 + m*32 covers K once
        int k = j * 4 + m * 32;
        float4 mv = *(const float4*)(mrow + k);
        float4 wv = *(const float4*)(sw + k);   // broadcast across b-groups
        acc += mv.x * wv.x + mv.y * wv.y + mv.z * wv.z + mv.w * wv.w;
    }
    acc += __shfl_xor(acc, 1);
    acc += __shfl_xor(acc, 2);
    acc += __shfl_xor(acc, 4);
    if (j == 0) out_attr[(size_t)b * A_ + a] = acc + attr_b[a];
}

// ---------------------------------------------- K_G: class = attr @ class_w.T
__global__ __launch_bounds__(256) void kG(
        const float* __restrict__ attr, const float* __restrict__ class_w,
        float* __restrict__ out_class) {
    int idx = blockIdx.x * 4 + (threadIdx.x >> 6);   // idx = b*200 + n
    int lane = threadIdx.x & 63;
    int b = idx / NC_, n = idx % NC_;
    float acc = 0.f;
    for (int a = lane; a < A_; a += 64)
        acc += attr[b * A_ + a] * class_w[n * A_ + a];
    acc += __shfl_xor(acc, 1);  acc += __shfl_xor(acc, 2);
    acc += __shfl_xor(acc, 4);  acc += __shfl_xor(acc, 8);
    acc += __shfl_xor(acc, 16); acc += __shfl_xor(acc, 32);
    if (lane == 0) out_class[idx] = acc;
}

extern "C" void kernel_launch(void* const* d_in, const int* in_sizes, int n_in,
                              void* d_out, int out_size, void* d_ws, size_t ws_size,
                              hipStream_t stream) {
    (void)in_sizes; (void)n_in; (void)out_size; (void)ws_size;
    const float* l3         = (const float*)d_in[0];
    const float* l4         = (const float*)d_in[1];
    const float* conv_w     = (const float*)d_in[2];
    const float* modulation = (const float*)d_in[3];
    const float* attr_w     = (const float*)d_in[4];
    const float* attr_b     = (const float*)d_in[5];
    const float* class_w    = (const float*)d_in[6];
    float* out = (float*)d_out;
    float* ws  = (float*)d_ws;
    float* asq    = ws + ASQ_OFF;
    float* mf     = ws + MF_OFF;
    float* logits = ws + LOGITS_OFF;
    float* Y      = ws + Y_OFF;
    float* Mp     = ws + MP_OFF;

    zK<<<285, 256, 0, stream>>>(conv_w, logits /* zero base: logits+Y */, asq);
    kA<<<2592, 256, 0, stream>>>(l3, l4, conv_w, logits, Y);
    kCD<<<B_, 256, 0, stream>>>(logits, Y, asq, out + MAPS_OFF, Mp);
    kE<<<1536, 256, 0, stream>>>(l3, l4, out + MAPS_OFF, Mp, modulation,
                                 out + AF_OFF, mf);
    kF<<<A_, 256, 0, stream>>>(mf, attr_w, attr_b, out + ATTR_OFF);
    kG<<<(B_ * NC_) / 4, 256, 0, stream>>>(out + ATTR_OFF, class_w,
                                           out + CLASS_OFF);
}